// Round 25
// baseline (98.231 us; speedup 1.0000x reference)
//
#include <hip/hip_runtime.h>
#include <stdint.h>

// VectorQuantizer — f32 I/O confirmed. d_in[0]=z [16384,64], d_in[1]=e [8192,64];
// d_out f32: [z_q 16384*64][idx-as-float 16384]. d_ws = 256MB confirmed.
//
// FROZEN exact numerics (fixup path only):
//   sz,se: scalar pairwise-8; c: 4 lanes (k mod 4), mul/add separately rounded,
//   16-chunks ascending, reversed sub-blocks (+12,+8,+4,+0), hadd (q0+q1)+(q2+q3);
//   A=fl(sz+se); d=fl(A-2c); argmin strict-<, first (smallest) index wins.
//
// Round-25 (r24 validated: scan->rowmax->rescan->fixup, 83.4us): mechanical
// cuts. (1) CPC=4: both MFMA passes load z-fragments once and loop 4 e-chunks
// (grid 64x16) -> zb L2 traffic 134MB->33MB per pass. (2) fixup fused into
// rescan epilogue (block exact-evals its own hbuf; ~27 hits/block); in-loop
// exec-masked exact fallback on HCAP overflow makes capture UNCONDITIONAL
// (fixes r24's silent-drop hazard). (3) 6 -> 5 kernel nodes. Frozen
// arithmetic, band bound (9.9e-5 < 1.25e-4), atomicMin combine unchanged.

#define NROWS 16384
#define NE    8192
#define D     64
#define BN    128
#define NCH   (NE / BN)     // 64
#define BAND  1.25e-4f
#define CPC   4             // chunks per block in MFMA passes
#define HCAP  512           // per-rescan-block hit capacity (E~27)

typedef __attribute__((ext_vector_type(8))) short short8;
typedef __attribute__((ext_vector_type(4))) float f32x4;

__device__ __forceinline__ uint32_t bf16rn(float f) {
    union { float f; uint32_t u; } c; c.f = f;
    return (c.u + 0x7FFFu + ((c.u >> 16) & 1u)) >> 16;
}
__device__ __forceinline__ uint32_t pk2(float lo, float hi) {
    return bf16rn(lo) | (bf16rn(hi) << 16);
}

// frozen-order exact eval + verified combine (cold path + epilogue)
__device__ __attribute__((noinline))
void fix_exact(int row, int j,
               const float* __restrict__ z, const float* __restrict__ e,
               const float* __restrict__ sz_arr, const float* __restrict__ se_arr,
               unsigned long long* __restrict__ packed)
{
    const float* zp = z + (size_t)row * D;
    const float* ep = e + (size_t)j * D;
    float q0 = 0.f, q1 = 0.f, q2 = 0.f, q3 = 0.f;
    #pragma unroll
    for (int cc = 0; cc < 4; ++cc) {
        #pragma unroll
        for (int sb = 3; sb >= 0; --sb) {
            const int b = cc * 16 + sb * 4;
            const float4 zv = *(const float4*)(zp + b);
            const float4 ev = *(const float4*)(ep + b);
            q0 = __fadd_rn(q0, __fmul_rn(zv.x, ev.x));
            q1 = __fadd_rn(q1, __fmul_rn(zv.y, ev.y));
            q2 = __fadd_rn(q2, __fmul_rn(zv.z, ev.z));
            q3 = __fadd_rn(q3, __fmul_rn(zv.w, ev.w));
        }
    }
    const float c = __fadd_rn(__fadd_rn(q0, q1), __fadd_rn(q2, q3));
    const float A = __fadd_rn(sz_arr[row], se_arr[j]);   // fl(sz + se)
    const float d = __fsub_rn(A, __fadd_rn(c, c));        // fl(A - 2c)
    const unsigned long long key =
        ((unsigned long long)__float_as_uint(d) << 32) | (unsigned int)j;
    atomicMin(packed + row, key);   // d>0 -> monotone bits; order-invariant
}

// ---------- phase 0: convert + exact prep + packed init ----------
__global__ __launch_bounds__(256)
void vq_convert_prep(const float* __restrict__ z, const float* __restrict__ e,
                     uint32_t* __restrict__ zb, uint32_t* __restrict__ eb,
                     float* __restrict__ sz_arr, float* __restrict__ se_arr,
                     unsigned long long* __restrict__ packed)
{
    if (blockIdx.x < 768) {
        const int i = blockIdx.x * 256 + threadIdx.x;
        const int nz = NROWS * D / 8;
        const int ne = NE * D / 8;
        if (i < nz) {
            const float4 a = ((const float4*)z)[i * 2];
            const float4 b = ((const float4*)z)[i * 2 + 1];
            uint4 o; o.x = pk2(a.x, a.y); o.y = pk2(a.z, a.w);
            o.z = pk2(b.x, b.y); o.w = pk2(b.z, b.w);
            ((uint4*)zb)[i] = o;
        } else if (i < nz + ne) {
            const int k = i - nz;
            const float4 a = ((const float4*)e)[k * 2];
            const float4 b = ((const float4*)e)[k * 2 + 1];
            uint4 o; o.x = pk2(a.x, a.y); o.y = pk2(a.z, a.w);
            o.z = pk2(b.x, b.y); o.w = pk2(b.z, b.w);
            ((uint4*)eb)[k] = o;
        }
    } else if (blockIdx.x < 1536) {
        const int pb   = blockIdx.x - 768;
        const int wave = threadIdx.x >> 6, lane = threadIdx.x & 63;
        const int g    = lane & 7;
        const int grow = pb * 32 + wave * 8 + (lane >> 3);
        const float* src = (grow < NROWS) ? z + (size_t)grow * D
                                          : e + (size_t)(grow - NROWS) * D;
        float acc = 0.f;
        #pragma unroll
        for (int i = 0; i < 8; ++i) {
            const float x = src[i * 8 + g];
            acc = __fadd_rn(acc, __fmul_rn(x, x));
        }
        const float s1 = __fadd_rn(acc, __shfl_xor(acc, 1, 64));
        const float s2 = __fadd_rn(s1,  __shfl_xor(s1, 2, 64));
        const float s4 = __fadd_rn(s2,  __shfl_xor(s2, 4, 64));
        if (g == 0) {
            if (grow < NROWS) sz_arr[grow] = s4;
            else              se_arr[grow - NROWS] = s4;
        }
    } else {
        const int i = (blockIdx.x - 1536) * 256 + threadIdx.x;
        packed[i] = 0xFFFFFFFFFFFFFFFFull;
    }
}

// ---------- phase 1: scan v3 — CPC=4 chunks/block, shfl-max reduce ----------
__global__ __launch_bounds__(256)
void vq_scan_mfma(const uint16_t* __restrict__ zb, const uint16_t* __restrict__ eb,
                  float* __restrict__ cmax)
{
    __shared__ uint16_t elds[BN][72];

    const int tid  = threadIdx.x;
    const int lane = tid & 63, w = tid >> 6;
    const int mb    = blockIdx.x;        // 0..63
    const int chgrp = blockIdx.y;        // 0..15
    const int row0 = mb * 256 + w * 64;
    const int l15  = lane & 15, l4 = lane >> 4;

    short8 af[4][2];                     // z-fragments loaded ONCE (32 VGPRs)
    #pragma unroll
    for (int m = 0; m < 4; ++m)
        #pragma unroll
        for (int h = 0; h < 2; ++h)
            af[m][h] = *(const short8*)(zb + (size_t)(row0 + m * 16 + l15) * D + h * 32 + l4 * 8);

    const f32x4 z4 = {0.f, 0.f, 0.f, 0.f};

    #pragma unroll 1
    for (int ci = 0; ci < CPC; ++ci) {
        const int ch = chgrp * CPC + ci;
        __syncthreads();   // prior iter's elds readers done
        {
            const int srow = tid >> 1, shalf = tid & 1;
            const uint16_t* sp = eb + (size_t)(ch * BN + srow) * D + shalf * 32;
            uint16_t* dp = &elds[srow][shalf * 32];
            #pragma unroll
            for (int q = 0; q < 4; ++q)
                *(short8*)(dp + q * 8) = *(const short8*)(sp + q * 8);
        }
        __syncthreads();

        f32x4 rm[4];
        #pragma unroll
        for (int m = 0; m < 4; ++m) rm[m] = {-3.0e38f, -3.0e38f, -3.0e38f, -3.0e38f};

        #pragma unroll 1
        for (int n = 0; n < 8; ++n) {
            const uint16_t* bp = &elds[n * 16 + l15][l4 * 8];
            const short8 b0 = *(const short8*)(bp);
            const short8 b1 = *(const short8*)(bp + 32);
            #pragma unroll
            for (int m = 0; m < 4; ++m) {
                f32x4 acc = __builtin_amdgcn_mfma_f32_16x16x32_bf16(af[m][0], b0, z4, 0, 0, 0);
                acc = __builtin_amdgcn_mfma_f32_16x16x32_bf16(af[m][1], b1, acc, 0, 0, 0);
                #pragma unroll
                for (int r = 0; r < 4; ++r) rm[m][r] = fmaxf(rm[m][r], acc[r]);
            }
        }

        #pragma unroll
        for (int m = 0; m < 4; ++m) {
            #pragma unroll
            for (int r = 0; r < 4; ++r) {
                #pragma unroll
                for (int o = 1; o < 16; o <<= 1)
                    rm[m][r] = fmaxf(rm[m][r], __shfl_xor(rm[m][r], o, 64));
            }
            if (l15 < 4) {
                const float v = (l15 == 0) ? rm[m][0] : (l15 == 1) ? rm[m][1]
                              : (l15 == 2) ? rm[m][2] : rm[m][3];
                cmax[(size_t)(row0 + m * 16 + l4 * 4 + l15) * NCH + ch] = v;
            }
        }
    }
}

// ---------- phase 2: per-row global max of c_bf16 ----------
__global__ __launch_bounds__(256)
void vq_rowmax(const float* __restrict__ cmax, float* __restrict__ rmax_arr)
{
    const int lane = threadIdx.x & 63, w = threadIdx.x >> 6;
    const int row = blockIdx.x * 4 + w;
    const float ci = cmax[(size_t)row * NCH + lane];
    float cm = ci;
    #pragma unroll
    for (int o = 1; o < 64; o <<= 1) cm = fmaxf(cm, __shfl_xor(cm, o, 64));
    if (lane == 0) rmax_arr[row] = cm;
}

// ---------- phase 3: rescan v3 — CPC=4, hit compaction + FUSED exact fixup ----------
__global__ __launch_bounds__(256)
void vq_rescan(const uint16_t* __restrict__ zb, const uint16_t* __restrict__ eb,
               const float* __restrict__ z, const float* __restrict__ e,
               const float* __restrict__ sz_arr, const float* __restrict__ se_arr,
               const float* __restrict__ rmax_arr,
               unsigned long long* __restrict__ packed)
{
    __shared__ uint16_t elds[BN][72];
    __shared__ uint32_t hbuf[HCAP];
    __shared__ uint32_t hcnt;

    const int tid  = threadIdx.x;
    const int lane = tid & 63, w = tid >> 6;
    const int mb    = blockIdx.x;        // 0..63
    const int chgrp = blockIdx.y;        // 0..15
    const int row0 = mb * 256 + w * 64;
    const int l15  = lane & 15, l4 = lane >> 4;

    if (tid == 0) hcnt = 0;

    short8 af[4][2];                     // z-fragments loaded ONCE
    #pragma unroll
    for (int m = 0; m < 4; ++m)
        #pragma unroll
        for (int h = 0; h < 2; ++h)
            af[m][h] = *(const short8*)(zb + (size_t)(row0 + m * 16 + l15) * D + h * 32 + l4 * 8);

    float th[4][4];                      // thresholds loaded ONCE (row-dependent)
    #pragma unroll
    for (int m = 0; m < 4; ++m)
        #pragma unroll
        for (int r = 0; r < 4; ++r)
            th[m][r] = rmax_arr[row0 + m * 16 + l4 * 4 + r] - BAND;

    const f32x4 z4 = {0.f, 0.f, 0.f, 0.f};

    #pragma unroll 1
    for (int ci = 0; ci < CPC; ++ci) {
        const int ch = chgrp * CPC + ci;
        __syncthreads();   // prior readers done; hcnt init visible (iter 0)
        {
            const int srow = tid >> 1, shalf = tid & 1;
            const uint16_t* sp = eb + (size_t)(ch * BN + srow) * D + shalf * 32;
            uint16_t* dp = &elds[srow][shalf * 32];
            #pragma unroll
            for (int q = 0; q < 4; ++q)
                *(short8*)(dp + q * 8) = *(const short8*)(sp + q * 8);
        }
        __syncthreads();

        #pragma unroll 1
        for (int n = 0; n < 8; ++n) {
            const uint16_t* bp = &elds[n * 16 + l15][l4 * 8];
            const short8 b0 = *(const short8*)(bp);
            const short8 b1 = *(const short8*)(bp + 32);
            const int jcol = ch * BN + n * 16 + l15;
            #pragma unroll
            for (int m = 0; m < 4; ++m) {
                f32x4 acc = __builtin_amdgcn_mfma_f32_16x16x32_bf16(af[m][0], b0, z4, 0, 0, 0);
                acc = __builtin_amdgcn_mfma_f32_16x16x32_bf16(af[m][1], b1, acc, 0, 0, 0);
                #pragma unroll
                for (int r = 0; r < 4; ++r) {
                    if (acc[r] >= th[m][r]) {   // rare (~27/block total)
                        const uint32_t row = (uint32_t)(row0 + m * 16 + l4 * 4 + r);
                        const uint32_t s = atomicAdd(&hcnt, 1u);
                        if (s < HCAP) hbuf[s] = (row << 13) | (uint32_t)jcol;
                        else fix_exact((int)row, jcol, z, e, sz_arr, se_arr, packed);
                        // ^ exec-masked cold path: capture is UNCONDITIONAL
                    }
                }
            }
        }
    }
    __syncthreads();

    // fused fixup epilogue: block exact-evals its own hits (frozen numerics)
    const uint32_t cnt = (hcnt < HCAP) ? hcnt : HCAP;
    for (uint32_t i = (uint32_t)tid; i < cnt; i += 256) {
        const uint32_t entry = hbuf[i];
        fix_exact((int)(entry >> 13), (int)(entry & 0x1FFFu),
                  z, e, sz_arr, se_arr, packed);
    }
}

// ---------- phase 4: z_q + idx from packed ----------
__global__ __launch_bounds__(256)
void vq_zq(const float* __restrict__ z, const float* __restrict__ e,
           const unsigned long long* __restrict__ packed, float* __restrict__ out)
{
    const size_t m = (size_t)blockIdx.x * 256 + threadIdx.x;
    const int r = (int)(m >> 6), k = (int)(m & 63);
    const int sel = (int)(packed[r] & 0xFFFFFFFFull);
    const float zv = z[m];
    const float ev = e[(size_t)sel * D + k];
    out[m] = __fadd_rn(zv, __fsub_rn(ev, zv));
    if (k == 0) out[(size_t)NROWS * D + r] = (float)sel;
}

extern "C" void kernel_launch(void* const* d_in, const int* in_sizes, int n_in,
                              void* d_out, int out_size, void* d_ws, size_t ws_size,
                              hipStream_t stream)
{
    const float* z = (const float*)d_in[0];
    const float* e = (const float*)d_in[1];
    float* out = (float*)d_out;

    char* ws = (char*)d_ws;
    const size_t MB = 1024 * 1024, KB = 1024;
    uint16_t* zb               = (uint16_t*)(ws);                         // 0..2 MB
    uint16_t* eb               = (uint16_t*)(ws + 2 * MB);                // 2..3 MB
    float* cmaxb               = (float*)(ws + 3 * MB);                   // 3..7 MB
    float* sz_arr              = (float*)(ws + 7 * MB);                   // 64 KB
    float* se_arr              = (float*)(ws + 7 * MB + 64 * KB);         // 32 KB
    float* rmax_arr            = (float*)(ws + 7 * MB + 128 * KB);        // 64 KB
    unsigned long long* packed = (unsigned long long*)(ws + 7 * MB + 256 * KB); // 128 KB

    vq_convert_prep<<<dim3(1600),            dim3(256), 0, stream>>>(z, e, (uint32_t*)zb, (uint32_t*)eb, sz_arr, se_arr, packed);
    vq_scan_mfma   <<<dim3(64, 16),          dim3(256), 0, stream>>>(zb, eb, cmaxb);
    vq_rowmax      <<<dim3(NROWS / 4),       dim3(256), 0, stream>>>(cmaxb, rmax_arr);
    vq_rescan      <<<dim3(64, 16),          dim3(256), 0, stream>>>(zb, eb, z, e, sz_arr, se_arr, rmax_arr, packed);
    vq_zq          <<<dim3(NROWS * D / 256), dim3(256), 0, stream>>>(z, e, packed, out);
}

// Round 26
// 74.020 us; speedup vs baseline: 1.3271x; 1.3271x over previous
//
#include <hip/hip_runtime.h>
#include <stdint.h>

// VectorQuantizer — f32 I/O confirmed. d_in[0]=z [16384,64], d_in[1]=e [8192,64];
// d_out f32: [z_q 16384*64][idx-as-float 16384]. d_ws = 256MB confirmed.
//
// FROZEN exact numerics (fixup path only):
//   sz,se: scalar pairwise-8; c: 4 lanes (k mod 4), mul/add separately rounded,
//   16-chunks ascending, reversed sub-blocks (+12,+8,+4,+0), hadd (q0+q1)+(q2+q3);
//   A=fl(sz+se); d=fl(A-2c); argmin strict-<, first (smallest) index wins.
//
// Round-26: r24's validated 4096-block shapes restored (r25 lesson: CPC=4 +
// in-loop noinline call cost +15us). Overhead cuts only:
//  (1) rowmax folded into scan via global atomicMax on order-isomorphic
//      uint-mapped floats (f>=0 -> bits|0x80000000, f<0 -> ~bits; monotone ->
//      rmax float bit-identical; max order-invariant -> deterministic).
//      Deletes rowmax kernel + 8MB cmax round-trip.
//  (2) fixup fused as rescan EPILOGUE only (~7 hits/block); HCAP=1024
//      (Poisson mean ~7 -> overflow prob ~e^-3000; r24 validated at 256).
//  Pipeline 6 -> 4 kernels. Frozen arithmetic/band/atomicMin unchanged.

#define NROWS 16384
#define NE    8192
#define D     64
#define BN    128
#define NCH   (NE / BN)     // 64
#define BAND  1.25e-4f
#define HCAP  1024

typedef __attribute__((ext_vector_type(8))) short short8;
typedef __attribute__((ext_vector_type(4))) float f32x4;

__device__ __forceinline__ uint32_t bf16rn(float f) {
    union { float f; uint32_t u; } c; c.f = f;
    return (c.u + 0x7FFFu + ((c.u >> 16) & 1u)) >> 16;
}
__device__ __forceinline__ uint32_t pk2(float lo, float hi) {
    return bf16rn(lo) | (bf16rn(hi) << 16);
}
// order-isomorphic float<->uint mapping (total order matches float <)
__device__ __forceinline__ uint32_t fkey(float f) {
    const uint32_t u = __float_as_uint(f);
    return (u & 0x80000000u) ? ~u : (u | 0x80000000u);
}
__device__ __forceinline__ float keyf(uint32_t k) {
    const uint32_t u = (k & 0x80000000u) ? (k ^ 0x80000000u) : ~k;
    return __uint_as_float(u);
}

// frozen-order exact eval + verified combine (epilogue only)
__device__ __attribute__((noinline))
void fix_exact(int row, int j,
               const float* __restrict__ z, const float* __restrict__ e,
               const float* __restrict__ sz_arr, const float* __restrict__ se_arr,
               unsigned long long* __restrict__ packed)
{
    const float* zp = z + (size_t)row * D;
    const float* ep = e + (size_t)j * D;
    float q0 = 0.f, q1 = 0.f, q2 = 0.f, q3 = 0.f;
    #pragma unroll
    for (int cc = 0; cc < 4; ++cc) {
        #pragma unroll
        for (int sb = 3; sb >= 0; --sb) {
            const int b = cc * 16 + sb * 4;
            const float4 zv = *(const float4*)(zp + b);
            const float4 ev = *(const float4*)(ep + b);
            q0 = __fadd_rn(q0, __fmul_rn(zv.x, ev.x));
            q1 = __fadd_rn(q1, __fmul_rn(zv.y, ev.y));
            q2 = __fadd_rn(q2, __fmul_rn(zv.z, ev.z));
            q3 = __fadd_rn(q3, __fmul_rn(zv.w, ev.w));
        }
    }
    const float c = __fadd_rn(__fadd_rn(q0, q1), __fadd_rn(q2, q3));
    const float A = __fadd_rn(sz_arr[row], se_arr[j]);   // fl(sz + se)
    const float d = __fsub_rn(A, __fadd_rn(c, c));        // fl(A - 2c)
    const unsigned long long key =
        ((unsigned long long)__float_as_uint(d) << 32) | (unsigned int)j;
    atomicMin(packed + row, key);   // d>0 -> monotone bits; order-invariant
}

// ---------- phase 0: convert + exact prep + packed/rmax init ----------
__global__ __launch_bounds__(256)
void vq_convert_prep(const float* __restrict__ z, const float* __restrict__ e,
                     uint32_t* __restrict__ zb, uint32_t* __restrict__ eb,
                     float* __restrict__ sz_arr, float* __restrict__ se_arr,
                     unsigned long long* __restrict__ packed,
                     uint32_t* __restrict__ rmax_u)
{
    if (blockIdx.x < 768) {
        const int i = blockIdx.x * 256 + threadIdx.x;
        const int nz = NROWS * D / 8;
        const int ne = NE * D / 8;
        if (i < nz) {
            const float4 a = ((const float4*)z)[i * 2];
            const float4 b = ((const float4*)z)[i * 2 + 1];
            uint4 o; o.x = pk2(a.x, a.y); o.y = pk2(a.z, a.w);
            o.z = pk2(b.x, b.y); o.w = pk2(b.z, b.w);
            ((uint4*)zb)[i] = o;
        } else if (i < nz + ne) {
            const int k = i - nz;
            const float4 a = ((const float4*)e)[k * 2];
            const float4 b = ((const float4*)e)[k * 2 + 1];
            uint4 o; o.x = pk2(a.x, a.y); o.y = pk2(a.z, a.w);
            o.z = pk2(b.x, b.y); o.w = pk2(b.z, b.w);
            ((uint4*)eb)[k] = o;
        }
    } else if (blockIdx.x < 1536) {
        const int pb   = blockIdx.x - 768;
        const int wave = threadIdx.x >> 6, lane = threadIdx.x & 63;
        const int g    = lane & 7;
        const int grow = pb * 32 + wave * 8 + (lane >> 3);
        const float* src = (grow < NROWS) ? z + (size_t)grow * D
                                          : e + (size_t)(grow - NROWS) * D;
        float acc = 0.f;
        #pragma unroll
        for (int i = 0; i < 8; ++i) {
            const float x = src[i * 8 + g];
            acc = __fadd_rn(acc, __fmul_rn(x, x));
        }
        const float s1 = __fadd_rn(acc, __shfl_xor(acc, 1, 64));
        const float s2 = __fadd_rn(s1,  __shfl_xor(s1, 2, 64));
        const float s4 = __fadd_rn(s2,  __shfl_xor(s2, 4, 64));
        if (g == 0) {
            if (grow < NROWS) sz_arr[grow] = s4;
            else              se_arr[grow - NROWS] = s4;
        }
    } else {   // 1536..1599: init packed + rmax keys (16384 each)
        const int i = (blockIdx.x - 1536) * 256 + threadIdx.x;
        packed[i] = 0xFFFFFFFFFFFFFFFFull;
        rmax_u[i] = 0u;                  // below every finite fkey
    }
}

// ---------- phase 1: scan (r24 shape) + fused global rmax atomicMax ----------
__global__ __launch_bounds__(256)
void vq_scan_mfma(const uint16_t* __restrict__ zb, const uint16_t* __restrict__ eb,
                  uint32_t* __restrict__ rmax_u)
{
    __shared__ uint16_t elds[BN][72];

    const int tid  = threadIdx.x;
    const int lane = tid & 63, w = tid >> 6;
    const int mb   = blockIdx.x >> 6;
    const int ch   = blockIdx.x & 63;
    const int row0 = mb * 256 + w * 64;
    const int l15  = lane & 15, l4 = lane >> 4;

    {
        const int srow = tid >> 1, shalf = tid & 1;
        const uint16_t* sp = eb + (size_t)(ch * BN + srow) * D + shalf * 32;
        uint16_t* dp = &elds[srow][shalf * 32];
        #pragma unroll
        for (int q = 0; q < 4; ++q)
            *(short8*)(dp + q * 8) = *(const short8*)(sp + q * 8);
    }

    short8 af[4][2];
    #pragma unroll
    for (int m = 0; m < 4; ++m)
        #pragma unroll
        for (int h = 0; h < 2; ++h)
            af[m][h] = *(const short8*)(zb + (size_t)(row0 + m * 16 + l15) * D + h * 32 + l4 * 8);

    __syncthreads();

    const f32x4 z4 = {0.f, 0.f, 0.f, 0.f};
    f32x4 rm[4];
    #pragma unroll
    for (int m = 0; m < 4; ++m) rm[m] = {-3.0e38f, -3.0e38f, -3.0e38f, -3.0e38f};

    #pragma unroll 1
    for (int n = 0; n < 8; ++n) {
        const uint16_t* bp = &elds[n * 16 + l15][l4 * 8];
        const short8 b0 = *(const short8*)(bp);
        const short8 b1 = *(const short8*)(bp + 32);
        #pragma unroll
        for (int m = 0; m < 4; ++m) {
            f32x4 acc = __builtin_amdgcn_mfma_f32_16x16x32_bf16(af[m][0], b0, z4, 0, 0, 0);
            acc = __builtin_amdgcn_mfma_f32_16x16x32_bf16(af[m][1], b1, acc, 0, 0, 0);
            #pragma unroll
            for (int r = 0; r < 4; ++r) rm[m][r] = fmaxf(rm[m][r], acc[r]);
        }
    }

    #pragma unroll
    for (int m = 0; m < 4; ++m) {
        #pragma unroll
        for (int r = 0; r < 4; ++r) {
            #pragma unroll
            for (int o = 1; o < 16; o <<= 1)
                rm[m][r] = fmaxf(rm[m][r], __shfl_xor(rm[m][r], o, 64));
        }
        if (l15 < 4) {
            const float v = (l15 == 0) ? rm[m][0] : (l15 == 1) ? rm[m][1]
                          : (l15 == 2) ? rm[m][2] : rm[m][3];
            atomicMax(rmax_u + (row0 + m * 16 + l4 * 4 + l15), fkey(v));
        }
    }
}

// ---------- phase 2: rescan (r24 shape) + fused fixup epilogue ----------
__global__ __launch_bounds__(256)
void vq_rescan(const uint16_t* __restrict__ zb, const uint16_t* __restrict__ eb,
               const float* __restrict__ z, const float* __restrict__ e,
               const float* __restrict__ sz_arr, const float* __restrict__ se_arr,
               const uint32_t* __restrict__ rmax_u,
               unsigned long long* __restrict__ packed)
{
    __shared__ uint16_t elds[BN][72];
    __shared__ uint32_t hbuf[HCAP];
    __shared__ uint32_t hcnt;

    const int tid  = threadIdx.x;
    const int lane = tid & 63, w = tid >> 6;
    const int mb   = blockIdx.x >> 6;
    const int ch   = blockIdx.x & 63;
    const int row0 = mb * 256 + w * 64;
    const int l15  = lane & 15, l4 = lane >> 4;

    if (tid == 0) hcnt = 0;
    {
        const int srow = tid >> 1, shalf = tid & 1;
        const uint16_t* sp = eb + (size_t)(ch * BN + srow) * D + shalf * 32;
        uint16_t* dp = &elds[srow][shalf * 32];
        #pragma unroll
        for (int q = 0; q < 4; ++q)
            *(short8*)(dp + q * 8) = *(const short8*)(sp + q * 8);
    }

    short8 af[4][2];
    #pragma unroll
    for (int m = 0; m < 4; ++m)
        #pragma unroll
        for (int h = 0; h < 2; ++h)
            af[m][h] = *(const short8*)(zb + (size_t)(row0 + m * 16 + l15) * D + h * 32 + l4 * 8);

    float th[4][4];   // thresholds (uniform across l15 -> L1 broadcast)
    #pragma unroll
    for (int m = 0; m < 4; ++m)
        #pragma unroll
        for (int r = 0; r < 4; ++r)
            th[m][r] = keyf(rmax_u[row0 + m * 16 + l4 * 4 + r]) - BAND;

    __syncthreads();

    const f32x4 z4 = {0.f, 0.f, 0.f, 0.f};
    #pragma unroll 1
    for (int n = 0; n < 8; ++n) {
        const uint16_t* bp = &elds[n * 16 + l15][l4 * 8];
        const short8 b0 = *(const short8*)(bp);
        const short8 b1 = *(const short8*)(bp + 32);
        const int jcol = ch * BN + n * 16 + l15;
        #pragma unroll
        for (int m = 0; m < 4; ++m) {
            f32x4 acc = __builtin_amdgcn_mfma_f32_16x16x32_bf16(af[m][0], b0, z4, 0, 0, 0);
            acc = __builtin_amdgcn_mfma_f32_16x16x32_bf16(af[m][1], b1, acc, 0, 0, 0);
            #pragma unroll
            for (int r = 0; r < 4; ++r) {
                if (acc[r] >= th[m][r]) {   // rare (~7/block)
                    const uint32_t row = (uint32_t)(row0 + m * 16 + l4 * 4 + r);
                    const uint32_t s = atomicAdd(&hcnt, 1u);
                    if (s < HCAP) hbuf[s] = (row << 13) | (uint32_t)jcol;
                }
            }
        }
    }
    __syncthreads();

    // fused fixup epilogue: frozen exact numerics on this block's hits
    const uint32_t cnt = (hcnt < HCAP) ? hcnt : HCAP;
    for (uint32_t i = (uint32_t)tid; i < cnt; i += 256) {
        const uint32_t entry = hbuf[i];
        fix_exact((int)(entry >> 13), (int)(entry & 0x1FFFu),
                  z, e, sz_arr, se_arr, packed);
    }
}

// ---------- phase 3: z_q + idx from packed ----------
__global__ __launch_bounds__(256)
void vq_zq(const float* __restrict__ z, const float* __restrict__ e,
           const unsigned long long* __restrict__ packed, float* __restrict__ out)
{
    const size_t m = (size_t)blockIdx.x * 256 + threadIdx.x;
    const int r = (int)(m >> 6), k = (int)(m & 63);
    const int sel = (int)(packed[r] & 0xFFFFFFFFull);
    const float zv = z[m];
    const float ev = e[(size_t)sel * D + k];
    out[m] = __fadd_rn(zv, __fsub_rn(ev, zv));
    if (k == 0) out[(size_t)NROWS * D + r] = (float)sel;
}

extern "C" void kernel_launch(void* const* d_in, const int* in_sizes, int n_in,
                              void* d_out, int out_size, void* d_ws, size_t ws_size,
                              hipStream_t stream)
{
    const float* z = (const float*)d_in[0];
    const float* e = (const float*)d_in[1];
    float* out = (float*)d_out;

    char* ws = (char*)d_ws;
    const size_t MB = 1024 * 1024, KB = 1024;
    uint16_t* zb               = (uint16_t*)(ws);                         // 0..2 MB
    uint16_t* eb               = (uint16_t*)(ws + 2 * MB);                // 2..3 MB
    float* sz_arr              = (float*)(ws + 3 * MB);                   // 64 KB
    float* se_arr              = (float*)(ws + 3 * MB + 64 * KB);         // 32 KB
    uint32_t* rmax_u           = (uint32_t*)(ws + 3 * MB + 128 * KB);     // 64 KB
    unsigned long long* packed = (unsigned long long*)(ws + 3 * MB + 256 * KB); // 128 KB

    vq_convert_prep<<<dim3(1600),            dim3(256), 0, stream>>>(z, e, (uint32_t*)zb, (uint32_t*)eb, sz_arr, se_arr, packed, rmax_u);
    vq_scan_mfma   <<<dim3(4096),            dim3(256), 0, stream>>>(zb, eb, rmax_u);
    vq_rescan      <<<dim3(4096),            dim3(256), 0, stream>>>(zb, eb, z, e, sz_arr, se_arr, rmax_u, packed);
    vq_zq          <<<dim3(NROWS * D / 256), dim3(256), 0, stream>>>(z, e, packed, out);
}

// Round 27
// 73.587 us; speedup vs baseline: 1.3349x; 1.0059x over previous
//
#include <hip/hip_runtime.h>
#include <stdint.h>

// VectorQuantizer — f32 I/O confirmed. d_in[0]=z [16384,64], d_in[1]=e [8192,64];
// d_out f32: [z_q 16384*64][idx-as-float 16384]. d_ws = 256MB confirmed.
//
// FROZEN exact numerics (fixup path only):
//   sz,se: scalar pairwise-8; c: 4 lanes (k mod 4), mul/add separately rounded,
//   16-chunks ascending, reversed sub-blocks (+12,+8,+4,+0), hadd (q0+q1)+(q2+q3);
//   A=fl(sz+se); d=fl(A-2c); argmin strict-<, first (smallest) index wins.
//
// Round-27 (r26 validated at 74.0us, 4 kernels): two mechanical cuts.
//  (1) CPC=2 in both MFMA passes (grid 64x32 = 2048 blocks): zb A-frag L2
//      traffic 134MB -> 67MB per pass. r25's regression causes excluded:
//      fixup stays EPILOGUE-ONLY (no in-loop noinline), 2048 not 1024 blocks,
//      HCAP=2048 (Poisson mean ~14 -> overflow impossible in practice; same
//      regime r24/r26 passed with).
//  (2) zq vectorized: thread = 4 consecutive floats (float4 gather/write).
// Frozen arithmetic, band bound, atomicMax/atomicMin combines unchanged
// (both order-invariant -> chunk-loop reordering is semantics-preserving).

#define NROWS 16384
#define NE    8192
#define D     64
#define BN    128
#define NCH   (NE / BN)     // 64
#define BAND  1.25e-4f
#define CPC   2
#define HCAP  2048

typedef __attribute__((ext_vector_type(8))) short short8;
typedef __attribute__((ext_vector_type(4))) float f32x4;

__device__ __forceinline__ uint32_t bf16rn(float f) {
    union { float f; uint32_t u; } c; c.f = f;
    return (c.u + 0x7FFFu + ((c.u >> 16) & 1u)) >> 16;
}
__device__ __forceinline__ uint32_t pk2(float lo, float hi) {
    return bf16rn(lo) | (bf16rn(hi) << 16);
}
// order-isomorphic float<->uint mapping (total order matches float <)
__device__ __forceinline__ uint32_t fkey(float f) {
    const uint32_t u = __float_as_uint(f);
    return (u & 0x80000000u) ? ~u : (u | 0x80000000u);
}
__device__ __forceinline__ float keyf(uint32_t k) {
    const uint32_t u = (k & 0x80000000u) ? (k ^ 0x80000000u) : ~k;
    return __uint_as_float(u);
}

// frozen-order exact eval + verified combine (epilogue only)
__device__ __attribute__((noinline))
void fix_exact(int row, int j,
               const float* __restrict__ z, const float* __restrict__ e,
               const float* __restrict__ sz_arr, const float* __restrict__ se_arr,
               unsigned long long* __restrict__ packed)
{
    const float* zp = z + (size_t)row * D;
    const float* ep = e + (size_t)j * D;
    float q0 = 0.f, q1 = 0.f, q2 = 0.f, q3 = 0.f;
    #pragma unroll
    for (int cc = 0; cc < 4; ++cc) {
        #pragma unroll
        for (int sb = 3; sb >= 0; --sb) {
            const int b = cc * 16 + sb * 4;
            const float4 zv = *(const float4*)(zp + b);
            const float4 ev = *(const float4*)(ep + b);
            q0 = __fadd_rn(q0, __fmul_rn(zv.x, ev.x));
            q1 = __fadd_rn(q1, __fmul_rn(zv.y, ev.y));
            q2 = __fadd_rn(q2, __fmul_rn(zv.z, ev.z));
            q3 = __fadd_rn(q3, __fmul_rn(zv.w, ev.w));
        }
    }
    const float c = __fadd_rn(__fadd_rn(q0, q1), __fadd_rn(q2, q3));
    const float A = __fadd_rn(sz_arr[row], se_arr[j]);   // fl(sz + se)
    const float d = __fsub_rn(A, __fadd_rn(c, c));        // fl(A - 2c)
    const unsigned long long key =
        ((unsigned long long)__float_as_uint(d) << 32) | (unsigned int)j;
    atomicMin(packed + row, key);   // d>0 -> monotone bits; order-invariant
}

// ---------- phase 0: convert + exact prep + packed/rmax init ----------
__global__ __launch_bounds__(256)
void vq_convert_prep(const float* __restrict__ z, const float* __restrict__ e,
                     uint32_t* __restrict__ zb, uint32_t* __restrict__ eb,
                     float* __restrict__ sz_arr, float* __restrict__ se_arr,
                     unsigned long long* __restrict__ packed,
                     uint32_t* __restrict__ rmax_u)
{
    if (blockIdx.x < 768) {
        const int i = blockIdx.x * 256 + threadIdx.x;
        const int nz = NROWS * D / 8;
        const int ne = NE * D / 8;
        if (i < nz) {
            const float4 a = ((const float4*)z)[i * 2];
            const float4 b = ((const float4*)z)[i * 2 + 1];
            uint4 o; o.x = pk2(a.x, a.y); o.y = pk2(a.z, a.w);
            o.z = pk2(b.x, b.y); o.w = pk2(b.z, b.w);
            ((uint4*)zb)[i] = o;
        } else if (i < nz + ne) {
            const int k = i - nz;
            const float4 a = ((const float4*)e)[k * 2];
            const float4 b = ((const float4*)e)[k * 2 + 1];
            uint4 o; o.x = pk2(a.x, a.y); o.y = pk2(a.z, a.w);
            o.z = pk2(b.x, b.y); o.w = pk2(b.z, b.w);
            ((uint4*)eb)[k] = o;
        }
    } else if (blockIdx.x < 1536) {
        const int pb   = blockIdx.x - 768;
        const int wave = threadIdx.x >> 6, lane = threadIdx.x & 63;
        const int g    = lane & 7;
        const int grow = pb * 32 + wave * 8 + (lane >> 3);
        const float* src = (grow < NROWS) ? z + (size_t)grow * D
                                          : e + (size_t)(grow - NROWS) * D;
        float acc = 0.f;
        #pragma unroll
        for (int i = 0; i < 8; ++i) {
            const float x = src[i * 8 + g];
            acc = __fadd_rn(acc, __fmul_rn(x, x));
        }
        const float s1 = __fadd_rn(acc, __shfl_xor(acc, 1, 64));
        const float s2 = __fadd_rn(s1,  __shfl_xor(s1, 2, 64));
        const float s4 = __fadd_rn(s2,  __shfl_xor(s2, 4, 64));
        if (g == 0) {
            if (grow < NROWS) sz_arr[grow] = s4;
            else              se_arr[grow - NROWS] = s4;
        }
    } else {
        const int i = (blockIdx.x - 1536) * 256 + threadIdx.x;
        packed[i] = 0xFFFFFFFFFFFFFFFFull;
        rmax_u[i] = 0u;
    }
}

// ---------- phase 1: scan — CPC=2, fused global rmax atomicMax ----------
__global__ __launch_bounds__(256)
void vq_scan_mfma(const uint16_t* __restrict__ zb, const uint16_t* __restrict__ eb,
                  uint32_t* __restrict__ rmax_u)
{
    __shared__ uint16_t elds[BN][72];

    const int tid  = threadIdx.x;
    const int lane = tid & 63, w = tid >> 6;
    const int mb   = blockIdx.x;         // 0..63
    const int cp   = blockIdx.y;         // 0..31 (chunk pair)
    const int row0 = mb * 256 + w * 64;
    const int l15  = lane & 15, l4 = lane >> 4;

    short8 af[4][2];                     // A-frags loaded ONCE per block
    #pragma unroll
    for (int m = 0; m < 4; ++m)
        #pragma unroll
        for (int h = 0; h < 2; ++h)
            af[m][h] = *(const short8*)(zb + (size_t)(row0 + m * 16 + l15) * D + h * 32 + l4 * 8);

    const f32x4 z4 = {0.f, 0.f, 0.f, 0.f};

    #pragma unroll 1
    for (int ci = 0; ci < CPC; ++ci) {
        const int ch = cp * CPC + ci;
        __syncthreads();   // prior iter's elds readers done (no-op iter 0)
        {
            const int srow = tid >> 1, shalf = tid & 1;
            const uint16_t* sp = eb + (size_t)(ch * BN + srow) * D + shalf * 32;
            uint16_t* dp = &elds[srow][shalf * 32];
            #pragma unroll
            for (int q = 0; q < 4; ++q)
                *(short8*)(dp + q * 8) = *(const short8*)(sp + q * 8);
        }
        __syncthreads();

        f32x4 rm[4];
        #pragma unroll
        for (int m = 0; m < 4; ++m) rm[m] = {-3.0e38f, -3.0e38f, -3.0e38f, -3.0e38f};

        #pragma unroll 1
        for (int n = 0; n < 8; ++n) {
            const uint16_t* bp = &elds[n * 16 + l15][l4 * 8];
            const short8 b0 = *(const short8*)(bp);
            const short8 b1 = *(const short8*)(bp + 32);
            #pragma unroll
            for (int m = 0; m < 4; ++m) {
                f32x4 acc = __builtin_amdgcn_mfma_f32_16x16x32_bf16(af[m][0], b0, z4, 0, 0, 0);
                acc = __builtin_amdgcn_mfma_f32_16x16x32_bf16(af[m][1], b1, acc, 0, 0, 0);
                #pragma unroll
                for (int r = 0; r < 4; ++r) rm[m][r] = fmaxf(rm[m][r], acc[r]);
            }
        }

        #pragma unroll
        for (int m = 0; m < 4; ++m) {
            #pragma unroll
            for (int r = 0; r < 4; ++r) {
                #pragma unroll
                for (int o = 1; o < 16; o <<= 1)
                    rm[m][r] = fmaxf(rm[m][r], __shfl_xor(rm[m][r], o, 64));
            }
            if (l15 < 4) {
                const float v = (l15 == 0) ? rm[m][0] : (l15 == 1) ? rm[m][1]
                              : (l15 == 2) ? rm[m][2] : rm[m][3];
                atomicMax(rmax_u + (row0 + m * 16 + l4 * 4 + l15), fkey(v));
            }
        }
    }
}

// ---------- phase 2: rescan — CPC=2, hit compaction + fixup epilogue ----------
__global__ __launch_bounds__(256)
void vq_rescan(const uint16_t* __restrict__ zb, const uint16_t* __restrict__ eb,
               const float* __restrict__ z, const float* __restrict__ e,
               const float* __restrict__ sz_arr, const float* __restrict__ se_arr,
               const uint32_t* __restrict__ rmax_u,
               unsigned long long* __restrict__ packed)
{
    __shared__ uint16_t elds[BN][72];
    __shared__ uint32_t hbuf[HCAP];
    __shared__ uint32_t hcnt;

    const int tid  = threadIdx.x;
    const int lane = tid & 63, w = tid >> 6;
    const int mb   = blockIdx.x;         // 0..63
    const int cp   = blockIdx.y;         // 0..31
    const int row0 = mb * 256 + w * 64;
    const int l15  = lane & 15, l4 = lane >> 4;

    if (tid == 0) hcnt = 0;

    short8 af[4][2];                     // A-frags loaded ONCE
    #pragma unroll
    for (int m = 0; m < 4; ++m)
        #pragma unroll
        for (int h = 0; h < 2; ++h)
            af[m][h] = *(const short8*)(zb + (size_t)(row0 + m * 16 + l15) * D + h * 32 + l4 * 8);

    float th[4][4];                      // thresholds loaded ONCE (global rmax)
    #pragma unroll
    for (int m = 0; m < 4; ++m)
        #pragma unroll
        for (int r = 0; r < 4; ++r)
            th[m][r] = keyf(rmax_u[row0 + m * 16 + l4 * 4 + r]) - BAND;

    const f32x4 z4 = {0.f, 0.f, 0.f, 0.f};

    #pragma unroll 1
    for (int ci = 0; ci < CPC; ++ci) {
        const int ch = cp * CPC + ci;
        __syncthreads();   // prior readers done; hcnt init visible
        {
            const int srow = tid >> 1, shalf = tid & 1;
            const uint16_t* sp = eb + (size_t)(ch * BN + srow) * D + shalf * 32;
            uint16_t* dp = &elds[srow][shalf * 32];
            #pragma unroll
            for (int q = 0; q < 4; ++q)
                *(short8*)(dp + q * 8) = *(const short8*)(sp + q * 8);
        }
        __syncthreads();

        #pragma unroll 1
        for (int n = 0; n < 8; ++n) {
            const uint16_t* bp = &elds[n * 16 + l15][l4 * 8];
            const short8 b0 = *(const short8*)(bp);
            const short8 b1 = *(const short8*)(bp + 32);
            const int jcol = ch * BN + n * 16 + l15;
            #pragma unroll
            for (int m = 0; m < 4; ++m) {
                f32x4 acc = __builtin_amdgcn_mfma_f32_16x16x32_bf16(af[m][0], b0, z4, 0, 0, 0);
                acc = __builtin_amdgcn_mfma_f32_16x16x32_bf16(af[m][1], b1, acc, 0, 0, 0);
                #pragma unroll
                for (int r = 0; r < 4; ++r) {
                    if (acc[r] >= th[m][r]) {   // rare (~14/block over 2 chunks)
                        const uint32_t row = (uint32_t)(row0 + m * 16 + l4 * 4 + r);
                        const uint32_t s = atomicAdd(&hcnt, 1u);
                        if (s < HCAP) hbuf[s] = (row << 13) | (uint32_t)jcol;
                    }
                }
            }
        }
    }
    __syncthreads();

    // fused fixup epilogue: frozen exact numerics on this block's hits
    const uint32_t cnt = (hcnt < HCAP) ? hcnt : HCAP;
    for (uint32_t i = (uint32_t)tid; i < cnt; i += 256) {
        const uint32_t entry = hbuf[i];
        fix_exact((int)(entry >> 13), (int)(entry & 0x1FFFu),
                  z, e, sz_arr, se_arr, packed);
    }
}

// ---------- phase 3: z_q + idx (vectorized: thread = 4 floats) ----------
__global__ __launch_bounds__(256)
void vq_zq(const float* __restrict__ z, const float* __restrict__ e,
           const unsigned long long* __restrict__ packed, float* __restrict__ out)
{
    const int q = blockIdx.x * 256 + threadIdx.x;     // 0..262143
    const int r = q >> 4, k4 = (q & 15) << 2;
    const int sel = (int)(packed[r] & 0xFFFFFFFFull); // broadcast across 16 thr
    const float4 zv = *(const float4*)(z + (size_t)r * D + k4);
    const float4 ev = *(const float4*)(e + (size_t)sel * D + k4);
    float4 o;
    o.x = __fadd_rn(zv.x, __fsub_rn(ev.x, zv.x));
    o.y = __fadd_rn(zv.y, __fsub_rn(ev.y, zv.y));
    o.z = __fadd_rn(zv.z, __fsub_rn(ev.z, zv.z));
    o.w = __fadd_rn(zv.w, __fsub_rn(ev.w, zv.w));
    *(float4*)(out + (size_t)r * D + k4) = o;
    if ((q & 15) == 0) out[(size_t)NROWS * D + r] = (float)sel;
}

extern "C" void kernel_launch(void* const* d_in, const int* in_sizes, int n_in,
                              void* d_out, int out_size, void* d_ws, size_t ws_size,
                              hipStream_t stream)
{
    const float* z = (const float*)d_in[0];
    const float* e = (const float*)d_in[1];
    float* out = (float*)d_out;

    char* ws = (char*)d_ws;
    const size_t MB = 1024 * 1024, KB = 1024;
    uint16_t* zb               = (uint16_t*)(ws);                         // 0..2 MB
    uint16_t* eb               = (uint16_t*)(ws + 2 * MB);                // 2..3 MB
    float* sz_arr              = (float*)(ws + 3 * MB);                   // 64 KB
    float* se_arr              = (float*)(ws + 3 * MB + 64 * KB);         // 32 KB
    uint32_t* rmax_u           = (uint32_t*)(ws + 3 * MB + 128 * KB);     // 64 KB
    unsigned long long* packed = (unsigned long long*)(ws + 3 * MB + 256 * KB); // 128 KB

    vq_convert_prep<<<dim3(1600),             dim3(256), 0, stream>>>(z, e, (uint32_t*)zb, (uint32_t*)eb, sz_arr, se_arr, packed, rmax_u);
    vq_scan_mfma   <<<dim3(64, 32),           dim3(256), 0, stream>>>(zb, eb, rmax_u);
    vq_rescan      <<<dim3(64, 32),           dim3(256), 0, stream>>>(zb, eb, z, e, sz_arr, se_arr, rmax_u, packed);
    vq_zq          <<<dim3(NROWS * 16 / 256), dim3(256), 0, stream>>>(z, e, packed, out);
}